// Round 5
// baseline (368.208 us; speedup 1.0000x reference)
//
#include <hip/hip_runtime.h>

// QuadConv R9: occupancy experiment — M-unroll 2 -> 1, 8 -> 12 waves/CU.
//  R8 post-mortem: doubling per-wave in-flight gathers gave only +9% (151->137)
//  => per-wave MLP depth saturated; binding limit is the outstanding-txn budget
//  at CU/SIMD level (per-CU ~64 txns x ~1.1Kcy avg service = observed 7.2 B/cy).
//  The untested axis is WAVE COUNT. M-unroll 1 halves acc (128->64 AGPR) and
//  LDS (16->8 KB/wave): total regs ~154 -> 3 waves/SIMD (launch_bounds(256,3)),
//  32 KB/block -> 3 blocks/CU = 12 waves/CU (+50%).
//  If in-flight budget scales with waves: qconv -> ~100-115 us.
//  If per-CU fixed: neutral (~135-150) -> R10 switches gather to reg-staging.
//
//  Distance-2 schedule identical in shape to R8; 4-wide staging counts:
//   prologue order: idx0(4) st0(4) st1(4) idx1(4) B0(4) B1(4)
//   even j=0: after st0: {st1 4, idx1 4, B 8}            = 16 -> wait 8
//   even j>0: after st(2j): odd(j-1) {B16, idx4, st4}    = 24 -> wait 16
//   odd  j=0: after st1: {idx1 4, B 8, evenB 16, st2 4}  = 32 -> wait 24
//   odd  j>0: after st(2j+1): even(j) {B16, st4}         = 20 -> wait 12
//  (margin-8 vs exact, tolerating compiler-inserted vmem; exact values in
//   comments. LGKM0 drains before every buffer overwrite as in R8.)

#define NPTS    262144
#define CIN     128
#define COUT    128
#define KNBR    9
#define KDIM    1152
#define NFRAGS  288
#define NFRAGS_PAD 296            // +2 t-groups so B(t+2) needs no guard
#define MT      128               // block tile rows (M-unroll 1: 4 waves x 32)
// zrow byte offset inside workspace: FEATB_BYTES + WP_BYTES
#define ZOFFB   67411968u         // 64*2^20 + 296*1024

typedef __bf16  bf16x8 __attribute__((ext_vector_type(8)));
typedef float   f32x4  __attribute__((ext_vector_type(4)));
typedef float   f32x16 __attribute__((ext_vector_type(16)));

// s_waitcnt imm: vmcnt[3:0]@[3:0], vmcnt[5:4]@[15:14], exp=7, lgkm=15 (no wait)
#define VMCNT(n) (((n) & 0xF) | (((n) >> 4) << 14) | (0xF << 8) | (7 << 4))
// lgkm=0 (wait all LDS), vmcnt=63 (no wait), exp=7
#define LGKM0    (0xF | (3 << 14) | (7 << 4))

// ---- pre-pass 1: features fp32 -> bf16 (nt loads: fp32 source is read once) ----
__global__ __launch_bounds__(256) void convert_feat_kernel(const float* __restrict__ f,
                                                           __bf16* __restrict__ fb) {
    size_t i = ((size_t)blockIdx.x * 256 + threadIdx.x) * 8;
    f32x4 a = __builtin_nontemporal_load((const f32x4*)(f + i));
    f32x4 b = __builtin_nontemporal_load((const f32x4*)(f + i + 4));
    bf16x8 o;
#pragma unroll
    for (int k = 0; k < 4; ++k) { o[k] = (__bf16)a[k]; o[k + 4] = (__bf16)b[k]; }
    *(bf16x8*)(fb + i) = o;
}

// ---- pre-pass 2: W -> bf16 MFMA B-fragment order (+ zero rows) ----
__global__ __launch_bounds__(256) void pack_w_kernel(const float* __restrict__ W,
                                                     __bf16* __restrict__ Wp,
                                                     __bf16* __restrict__ zrow_b) {
    if (blockIdx.x == NFRAGS / 4) {
        int t = threadIdx.x;
        if (t < CIN) zrow_b[t] = (__bf16)0.f;
        return;
    }
    int t    = blockIdx.x * 256 + threadIdx.x;
    int lane = t & 63;
    int frag = t >> 6;
    int nt = frag & 3;
    int ks = frag >> 2;
    int n  = nt * 32 + (lane & 31);
    int k0 = ks * 16 + (lane >> 5) * 8;
    const f32x4* src = (const f32x4*)(W + (size_t)n * KDIM + k0);
    f32x4 v0 = src[0], v1 = src[1];
    bf16x8 o;
#pragma unroll
    for (int i = 0; i < 4; ++i) { o[i] = (__bf16)v0[i]; o[i + 4] = (__bf16)v1[i]; }
    *(bf16x8*)(Wp + (size_t)frag * 512 + lane * 8) = o;
}

// ---- main kernel ----
__global__ __launch_bounds__(256, 3) void qconv_kernel(
    const __bf16* __restrict__ featb,  // [NPTS,128] bf16 (= workspace base)
    const int*    __restrict__ nidx,   // [NPTS,9]
    const __bf16* __restrict__ Wp,     // packed B-fragments (padded)
    const float*  __restrict__ bias,
    float*        __restrict__ out)
{
    // per-wave: 2 bufs x 4 KB (32 rows x 128 B half-row windows); block 32 KB
    __shared__ __align__(16) char lds_raw[4 * 2 * 4096];

    const int tid  = threadIdx.x;
    const int lane = tid & 63;
    const int wave = tid >> 6;
    const int l31  = lane & 31;
    const int half = lane >> 5;
    const int rb   = blockIdx.x * MT;
    char* myLds = lds_raw + wave * 8192;

    // staging role: 8 lanes per row, lane covers swizzled 16B chunk of 128B window
    const int srow = lane >> 3;   // row within 8-row group
    const int schk = lane & 7;    // LDS slot; fetches global chunk schk^srow
    const int sxor = (schk ^ srow) * 16;   // byte offset of fetched global chunk

    // idx base: row-group n (0..3) covers rows rb + wave*32 + n*8 + srow
    const int* ia = nidx + (size_t)(rb + wave * 32 + srow) * KNBR;

    f32x16 acc[4];
#pragma unroll
    for (int a = 0; a < 4; ++a)
#pragma unroll
        for (int i = 0; i < 16; ++i) acc[a][i] = 0.f;

    int      NPidx[4];   // raw indices (transient)
    unsigned NPoff[4];   // byte offsets into workspace for rows being staged
    bf16x8 Bb[3][4];     // B register ring

    auto loadIdx = [&](int jn) {
#pragma unroll
        for (int n = 0; n < 4; ++n)
            NPidx[n] = ia[n * 8 * KNBR + jn];
    };
    auto convertP = [&](void) {
#pragma unroll
        for (int n = 0; n < 4; ++n)
            NPoff[n] = (NPidx[n] >= 0) ? ((unsigned)NPidx[n] << 8) : ZOFFB;
    };
    // stage chunk c (half-row (c&1) of current j): 4 fire-and-forget 1KB DMAs
    auto stage_chunk = [&](int c) {
        const int eoff = (c & 1) * 128 + sxor;   // bytes within the 256-B row
#pragma unroll
        for (int n = 0; n < 4; ++n) {
            const char* g = (const char*)featb + (NPoff[n] + eoff);
            char* dst = myLds + (c & 1) * 4096 + n * 1024;
            __builtin_amdgcn_global_load_lds(
                (const __attribute__((address_space(1))) void*)g,
                (__attribute__((address_space(3))) void*)dst,
                16, 0, 0);
        }
    };
    auto issueB = [&](int t) {
#pragma unroll
        for (int nt = 0; nt < 4; ++nt)
            Bb[t % 3][nt] = *(const bf16x8*)(Wp + (size_t)(t * 4 + nt) * 512 + lane * 8);
    };
    auto readA = [&](int buf, int ksl) -> bf16x8 {
        const int s = (ksl * 2 + half) ^ (l31 & 7);
        return *(const bf16x8*)(myLds + buf * 4096 + l31 * 128 + s * 16);
    };

    // ---- prologue: issue order pinned = idx0 st0 st1 idx1 B0 B1 ----
    loadIdx(0);
    convertP();                                        // (waits idx0; once)
    __builtin_amdgcn_sched_barrier(0);
    stage_chunk(0);
    __builtin_amdgcn_sched_barrier(0);
    stage_chunk(1);
    __builtin_amdgcn_sched_barrier(0);
    loadIdx(1);
    __builtin_amdgcn_sched_barrier(0);
    issueB(0); issueB(1);

    // ---- main loop: 9 j's x 2 chunks, distance-2 staging; fully unrolled ----
#pragma unroll
    for (int j = 0; j < KNBR; ++j) {
        // ===== even chunk c = 2j (buf0) =====
        __builtin_amdgcn_sched_barrier(0);
        if (j == 0) __builtin_amdgcn_s_waitcnt(VMCNT(8));    // exact 16, margin 8
        else        __builtin_amdgcn_s_waitcnt(VMCNT(16));   // exact 24, margin 8
        __builtin_amdgcn_sched_barrier(0);
#pragma unroll
        for (int ksl = 0; ksl < 4; ++ksl) {
            const int t = j * 8 + ksl;
            issueB(t + 2);
            bf16x8 a0 = readA(0, ksl);
            if (ksl == 3) {
                // all 4 ds_reads of buf0 issued; drain them -> buf0 is free,
                // then overwrite it with chunk 2j+2 (j+1's even chunk).
                __builtin_amdgcn_sched_barrier(0);
                __builtin_amdgcn_s_waitcnt(LGKM0);
                __builtin_amdgcn_sched_barrier(0);
                convertP();                    // NPoff <- rows of j+1 (clamped idx)
                stage_chunk(2 * j + 2);        // j=8: dummy (valid mem, unused)
                __builtin_amdgcn_sched_barrier(0);
            }
#pragma unroll
            for (int nt = 0; nt < 4; ++nt)
                acc[nt] = __builtin_amdgcn_mfma_f32_32x32x16_bf16(a0, Bb[t % 3][nt], acc[nt], 0, 0, 0);
        }
        // ===== odd chunk c = 2j+1 (buf1) =====
        __builtin_amdgcn_sched_barrier(0);
        if (j == 0) __builtin_amdgcn_s_waitcnt(VMCNT(24));   // exact 32, margin 8
        else        __builtin_amdgcn_s_waitcnt(VMCNT(12));   // exact 20, margin 8
        __builtin_amdgcn_sched_barrier(0);
#pragma unroll
        for (int ksl = 4; ksl < 8; ++ksl) {
            const int t = j * 8 + ksl;
            issueB(t + 2);
            bf16x8 a0 = readA(1, ksl - 4);
            if (ksl == 7) {
                __builtin_amdgcn_sched_barrier(0);
                __builtin_amdgcn_s_waitcnt(LGKM0);
                __builtin_amdgcn_sched_barrier(0);
                // idx for j+2 (clamped); consumed by convertP at even(j+1)
                loadIdx((j + 2 <= KNBR - 1) ? j + 2 : KNBR - 1);
                stage_chunk(2 * j + 3);        // odd chunk of j+1 (j=8: dummy)
                __builtin_amdgcn_sched_barrier(0);
            }
#pragma unroll
            for (int nt = 0; nt < 4; ++nt)
                acc[nt] = __builtin_amdgcn_mfma_f32_32x32x16_bf16(a0, Bb[t % 3][nt], acc[nt], 0, 0, 0);
        }
    }

    // drain all outstanding vmem (incl. the two dummy tail stages) before the
    // wave can exit and its LDS be re-allocated to another block.
    __builtin_amdgcn_sched_barrier(0);
    __builtin_amdgcn_s_waitcnt(VMCNT(0));
    __builtin_amdgcn_sched_barrier(0);

    // ---- epilogue: C/D layout col=lane&31, row=(r&3)+8*(r>>2)+4*half ----
#pragma unroll
    for (int nt = 0; nt < 4; ++nt) {
        const int col = nt * 32 + l31;
        const float bv = bias[col];
#pragma unroll
        for (int r = 0; r < 16; ++r) {
            const int row = (r & 3) + 8 * (r >> 2) + 4 * half;
            __builtin_nontemporal_store(acc[nt][r] + bv,
                &out[(size_t)(rb + wave * 32 + row) * COUT + col]);
        }
    }
}

// ---- safety fallback (never expected to run; ws_size has been ~>64MiB) ----
__global__ void qconv_naive(const float* __restrict__ feat, const int* __restrict__ nidx,
                            const float* __restrict__ W, const float* __restrict__ bias,
                            float* __restrict__ out) {
    int p = blockIdx.x, c = threadIdx.x;
    float s = bias[c];
    for (int j = 0; j < KNBR; ++j) {
        int g = nidx[(size_t)p * KNBR + j];
        if (g < 0) continue;
        const float* fr = feat + (size_t)g * CIN;
        const float* wr = W + (size_t)c * KDIM + j * CIN;
        for (int k = 0; k < CIN; ++k) s += fr[k] * wr[k];
    }
    out[(size_t)p * COUT + c] = s;
}

extern "C" void kernel_launch(void* const* d_in, const int* in_sizes, int n_in,
                              void* d_out, int out_size, void* d_ws, size_t ws_size,
                              hipStream_t stream) {
    const float* feat = (const float*)d_in[0];
    const int*   nidx = (const int*)d_in[1];
    const float* W    = (const float*)d_in[2];
    const float* bias = (const float*)d_in[3];
    float*       out  = (float*)d_out;

    const size_t FEATB_BYTES = (size_t)NPTS * CIN * 2;        // 64 MiB
    const size_t WP_BYTES    = (size_t)NFRAGS_PAD * 512 * 2;  // 296 KiB
    // NOTE: zrow sits at d_ws + FEATB_BYTES + WP_BYTES == d_ws + ZOFFB (kernel
    // addresses it as featb-base + ZOFFB; keep these in sync).

    if (ws_size >= FEATB_BYTES + WP_BYTES + 512) {
        __bf16* featb  = (__bf16*)d_ws;
        __bf16* Wp     = (__bf16*)((char*)d_ws + FEATB_BYTES);
        __bf16* zrow_b = (__bf16*)((char*)d_ws + FEATB_BYTES + WP_BYTES);
        convert_feat_kernel<<<NPTS * CIN / (256 * 8), 256, 0, stream>>>(feat, featb);
        pack_w_kernel<<<NFRAGS / 4 + 1, 256, 0, stream>>>(W, Wp, zrow_b);
        qconv_kernel<<<NPTS / MT, 256, 0, stream>>>(featb, nidx, Wp, bias, out);
    } else {
        qconv_naive<<<NPTS, COUT, 0, stream>>>(feat, nidx, W, bias, out);
    }
}

// Round 6
// 342.054 us; speedup vs baseline: 1.0765x; 1.0765x over previous
//
#include <hip/hip_runtime.h>

// QuadConv R10: revert to R8 (best: 137 us qconv / 345 headline) + compile-time
// skip of the j=8 dummy tail stages.
//  R9 post-mortem: +50% occupancy REGRESSED (162 us, BW 3.39). vmcnt counts
//  instructions but each global_load_lds = 8 independent 128B line-requests;
//  R8 already demanded ~1024 lines in flight per CU >> MSHR capacity. The CU
//  miss-handling/fabric path is saturated: 3.8 TB/s is the service ceiling for
//  random 128B gathers. Fetch (328 MB) sits at the XCD-dilution floor (~330);
//  qconv 137 us vs ~132 us pattern roofline. So: restore R8, trim the only
//  remaining pure waste (2 dummy stage chunks at j=8: 16 DMAs/wave, ~32 MB).
//  Tail-skip is safe: loop is fully unrolled (j compile-time), and removing
//  trailing stages only lowers outstanding counts -> existing waits remain
//  correct (FIFO vmcnt retirement).
//  Predict: qconv 134-138, FETCH ~325 MB, BW ~3.8, headline ~342-346.
//
//  Exact vmcnt bounds (ops issued after the stage that must retire):
//   even j=0: {st1 8, idx1 8, B0/B1 8}                = 24 -> wait 16
//   even j>0: odd(j-1) {B 16, idx 8, st 8}            = 32 -> wait 24
//   odd  j=0: {idx1 8, B 8, evenB 16, st2 8}          = 40 -> wait 32
//   odd  j>0: even(j) {B 16, st 8}                    = 24 -> wait 16
//  (margin-8 vs exact, tolerating compiler-inserted vmem. LGKM0 drains before
//   every buffer overwrite. With the j=8 skip, later waits are conservative.)

#define NPTS    262144
#define CIN     128
#define COUT    128
#define KNBR    9
#define KDIM    1152
#define NFRAGS  288
#define NFRAGS_PAD 296            // +2 t-groups so B(t+2) needs no guard
#define MT      256
// zrow byte offset inside workspace: FEATB_BYTES + WP_BYTES
#define ZOFFB   67411968u         // 64*2^20 + 296*1024

typedef __bf16  bf16x8 __attribute__((ext_vector_type(8)));
typedef float   f32x4  __attribute__((ext_vector_type(4)));
typedef float   f32x16 __attribute__((ext_vector_type(16)));

// s_waitcnt imm: vmcnt[3:0]@[3:0], vmcnt[5:4]@[15:14], exp=7, lgkm=15 (no wait)
#define VMCNT(n) (((n) & 0xF) | (((n) >> 4) << 14) | (0xF << 8) | (7 << 4))
// lgkm=0 (wait all LDS), vmcnt=63 (no wait), exp=7
#define LGKM0    (0xF | (3 << 14) | (7 << 4))

// ---- pre-pass 1: features fp32 -> bf16 (nt loads: fp32 source is read once) ----
__global__ __launch_bounds__(256) void convert_feat_kernel(const float* __restrict__ f,
                                                           __bf16* __restrict__ fb) {
    size_t i = ((size_t)blockIdx.x * 256 + threadIdx.x) * 8;
    f32x4 a = __builtin_nontemporal_load((const f32x4*)(f + i));
    f32x4 b = __builtin_nontemporal_load((const f32x4*)(f + i + 4));
    bf16x8 o;
#pragma unroll
    for (int k = 0; k < 4; ++k) { o[k] = (__bf16)a[k]; o[k + 4] = (__bf16)b[k]; }
    *(bf16x8*)(fb + i) = o;
}

// ---- pre-pass 2: W -> bf16 MFMA B-fragment order (+ zero rows) ----
__global__ __launch_bounds__(256) void pack_w_kernel(const float* __restrict__ W,
                                                     __bf16* __restrict__ Wp,
                                                     __bf16* __restrict__ zrow_b) {
    if (blockIdx.x == NFRAGS / 4) {
        int t = threadIdx.x;
        if (t < CIN) zrow_b[t] = (__bf16)0.f;
        return;
    }
    int t    = blockIdx.x * 256 + threadIdx.x;
    int lane = t & 63;
    int frag = t >> 6;
    int nt = frag & 3;
    int ks = frag >> 2;
    int n  = nt * 32 + (lane & 31);
    int k0 = ks * 16 + (lane >> 5) * 8;
    const f32x4* src = (const f32x4*)(W + (size_t)n * KDIM + k0);
    f32x4 v0 = src[0], v1 = src[1];
    bf16x8 o;
#pragma unroll
    for (int i = 0; i < 4; ++i) { o[i] = (__bf16)v0[i]; o[i + 4] = (__bf16)v1[i]; }
    *(bf16x8*)(Wp + (size_t)frag * 512 + lane * 8) = o;
}

// ---- main kernel ----
__global__ __launch_bounds__(256, 2) void qconv_kernel(
    const __bf16* __restrict__ featb,  // [NPTS,128] bf16 (= workspace base)
    const int*    __restrict__ nidx,   // [NPTS,9]
    const __bf16* __restrict__ Wp,     // packed B-fragments (padded)
    const float*  __restrict__ bias,
    float*        __restrict__ out)
{
    // per-wave: 2 bufs x 2 tiles x 4 KB (32 rows x 128 B half-row windows)
    __shared__ __align__(16) char lds_raw[4 * 2 * 2 * 4096];

    const int tid  = threadIdx.x;
    const int lane = tid & 63;
    const int wave = tid >> 6;
    const int l31  = lane & 31;
    const int half = lane >> 5;
    const int rb   = blockIdx.x * MT;
    char* myLds = lds_raw + wave * 16384;

    // staging role: 8 lanes per row, lane covers swizzled 16B chunk of 128B window
    const int srow = lane >> 3;   // row within 8-row group
    const int schk = lane & 7;    // LDS slot; fetches global chunk schk^srow
    const int sxor = (schk ^ srow) * 16;   // byte offset of fetched global chunk

    // idx bases: row-group n covers rows rb + (n>>2)*128 + wave*32 + (n&3)*8 + srow
    const int* iab0 = nidx + (size_t)(rb + wave * 32 + srow) * KNBR;
    const int* iab1 = iab0 + 128 * KNBR;

    f32x16 acc[8];
#pragma unroll
    for (int a = 0; a < 8; ++a)
#pragma unroll
        for (int i = 0; i < 16; ++i) acc[a][i] = 0.f;

    int      NPidx[8];   // raw indices (transient)
    unsigned NPoff[8];   // byte offsets into workspace for rows being staged
    bf16x8 Bb[3][4];     // B register ring

    auto loadIdx = [&](int jn) {
#pragma unroll
        for (int n = 0; n < 8; ++n)
            NPidx[n] = ((n >> 2) ? iab1 : iab0)[(n & 3) * 8 * KNBR + jn];
    };
    auto convertP = [&](void) {
#pragma unroll
        for (int n = 0; n < 8; ++n)
            NPoff[n] = (NPidx[n] >= 0) ? ((unsigned)NPidx[n] << 8) : ZOFFB;
    };
    // stage chunk c (half-row (c&1) of current j): 8 fire-and-forget 1KB DMAs
    auto stage_chunk = [&](int c) {
        const int eoff = (c & 1) * 128 + sxor;   // bytes within the 256-B row
#pragma unroll
        for (int n = 0; n < 8; ++n) {
            const char* g = (const char*)featb + (NPoff[n] + eoff);
            char* dst = myLds + (c & 1) * 8192 + (n >> 2) * 4096 + (n & 3) * 1024;
            __builtin_amdgcn_global_load_lds(
                (const __attribute__((address_space(1))) void*)g,
                (__attribute__((address_space(3))) void*)dst,
                16, 0, 0);
        }
    };
    auto issueB = [&](int t) {
#pragma unroll
        for (int nt = 0; nt < 4; ++nt)
            Bb[t % 3][nt] = *(const bf16x8*)(Wp + (size_t)(t * 4 + nt) * 512 + lane * 8);
    };
    auto readA = [&](int buf, int T, int ksl) -> bf16x8 {
        const int s = (ksl * 2 + half) ^ (l31 & 7);
        return *(const bf16x8*)(myLds + buf * 8192 + T * 4096 + l31 * 128 + s * 16);
    };

    // ---- prologue: issue order pinned = idx0 st0 st1 idx1 B0 B1 ----
    loadIdx(0);
    convertP();                                        // (waits idx0; once)
    __builtin_amdgcn_sched_barrier(0);
    stage_chunk(0);
    __builtin_amdgcn_sched_barrier(0);
    stage_chunk(1);
    __builtin_amdgcn_sched_barrier(0);
    loadIdx(1);
    __builtin_amdgcn_sched_barrier(0);
    issueB(0); issueB(1);

    // ---- main loop: 9 j's x 2 chunks, distance-2 staging; fully unrolled ----
#pragma unroll
    for (int j = 0; j < KNBR; ++j) {
        // ===== even chunk c = 2j (buf0) =====
        __builtin_amdgcn_sched_barrier(0);
        if (j == 0) __builtin_amdgcn_s_waitcnt(VMCNT(16));   // exact 24, margin 8
        else        __builtin_amdgcn_s_waitcnt(VMCNT(24));   // exact 32, margin 8
        __builtin_amdgcn_sched_barrier(0);
#pragma unroll
        for (int ksl = 0; ksl < 4; ++ksl) {
            const int t = j * 8 + ksl;
            issueB(t + 2);
            bf16x8 a0 = readA(0, 0, ksl);
            bf16x8 a1 = readA(0, 1, ksl);
            if (ksl == 3 && j < KNBR - 1) {
                // all 8 ds_reads of buf0 issued; drain them -> buf0 is free,
                // then overwrite it with chunk 2j+2 (j+1's even chunk).
                // j=8: skipped entirely (no dummy stage; waits stay valid).
                __builtin_amdgcn_sched_barrier(0);
                __builtin_amdgcn_s_waitcnt(LGKM0);
                __builtin_amdgcn_sched_barrier(0);
                convertP();                    // NPoff <- rows of j+1
                stage_chunk(2 * j + 2);
                __builtin_amdgcn_sched_barrier(0);
            }
#pragma unroll
            for (int nt = 0; nt < 4; ++nt) {
                acc[nt]     = __builtin_amdgcn_mfma_f32_32x32x16_bf16(a0, Bb[t % 3][nt], acc[nt], 0, 0, 0);
                acc[4 + nt] = __builtin_amdgcn_mfma_f32_32x32x16_bf16(a1, Bb[t % 3][nt], acc[4 + nt], 0, 0, 0);
            }
        }
        // ===== odd chunk c = 2j+1 (buf1) =====
        __builtin_amdgcn_sched_barrier(0);
        if (j == 0) __builtin_amdgcn_s_waitcnt(VMCNT(32));   // exact 40, margin 8
        else        __builtin_amdgcn_s_waitcnt(VMCNT(16));   // exact 24, margin 8
        __builtin_amdgcn_sched_barrier(0);
#pragma unroll
        for (int ksl = 4; ksl < 8; ++ksl) {
            const int t = j * 8 + ksl;
            issueB(t + 2);
            bf16x8 a0 = readA(1, 0, ksl - 4);
            bf16x8 a1 = readA(1, 1, ksl - 4);
            if (ksl == 7 && j < KNBR - 1) {
                __builtin_amdgcn_sched_barrier(0);
                __builtin_amdgcn_s_waitcnt(LGKM0);
                __builtin_amdgcn_sched_barrier(0);
                // idx for j+2 (clamped); consumed by convertP at even(j+1)
                loadIdx((j + 2 <= KNBR - 1) ? j + 2 : KNBR - 1);
                stage_chunk(2 * j + 3);
                __builtin_amdgcn_sched_barrier(0);
            }
#pragma unroll
            for (int nt = 0; nt < 4; ++nt) {
                acc[nt]     = __builtin_amdgcn_mfma_f32_32x32x16_bf16(a0, Bb[t % 3][nt], acc[nt], 0, 0, 0);
                acc[4 + nt] = __builtin_amdgcn_mfma_f32_32x32x16_bf16(a1, Bb[t % 3][nt], acc[4 + nt], 0, 0, 0);
            }
        }
    }

    // drain all outstanding vmem (trailing B loads) before epilogue/exit.
    __builtin_amdgcn_sched_barrier(0);
    __builtin_amdgcn_s_waitcnt(VMCNT(0));
    __builtin_amdgcn_sched_barrier(0);

    // ---- epilogue: C/D layout col=lane&31, row=(r&3)+8*(r>>2)+4*half ----
#pragma unroll
    for (int nt = 0; nt < 4; ++nt) {
        const int col = nt * 32 + l31;
        const float bv = bias[col];
#pragma unroll
        for (int r = 0; r < 16; ++r) {
            const int row = (r & 3) + 8 * (r >> 2) + 4 * half;
            __builtin_nontemporal_store(acc[nt][r] + bv,
                &out[(size_t)(rb + wave * 32 + row) * COUT + col]);
            __builtin_nontemporal_store(acc[4 + nt][r] + bv,
                &out[(size_t)(rb + 128 + wave * 32 + row) * COUT + col]);
        }
    }
}

// ---- safety fallback (never expected to run; ws_size has been ~>64MiB) ----
__global__ void qconv_naive(const float* __restrict__ feat, const int* __restrict__ nidx,
                            const float* __restrict__ W, const float* __restrict__ bias,
                            float* __restrict__ out) {
    int p = blockIdx.x, c = threadIdx.x;
    float s = bias[c];
    for (int j = 0; j < KNBR; ++j) {
        int g = nidx[(size_t)p * KNBR + j];
        if (g < 0) continue;
        const float* fr = feat + (size_t)g * CIN;
        const float* wr = W + (size_t)c * KDIM + j * CIN;
        for (int k = 0; k < CIN; ++k) s += fr[k] * wr[k];
    }
    out[(size_t)p * COUT + c] = s;
}

extern "C" void kernel_launch(void* const* d_in, const int* in_sizes, int n_in,
                              void* d_out, int out_size, void* d_ws, size_t ws_size,
                              hipStream_t stream) {
    const float* feat = (const float*)d_in[0];
    const int*   nidx = (const int*)d_in[1];
    const float* W    = (const float*)d_in[2];
    const float* bias = (const float*)d_in[3];
    float*       out  = (float*)d_out;

    const size_t FEATB_BYTES = (size_t)NPTS * CIN * 2;        // 64 MiB
    const size_t WP_BYTES    = (size_t)NFRAGS_PAD * 512 * 2;  // 296 KiB
    // NOTE: zrow sits at d_ws + FEATB_BYTES + WP_BYTES == d_ws + ZOFFB (kernel
    // addresses it as featb-base + ZOFFB; keep these in sync).

    if (ws_size >= FEATB_BYTES + WP_BYTES + 512) {
        __bf16* featb  = (__bf16*)d_ws;
        __bf16* Wp     = (__bf16*)((char*)d_ws + FEATB_BYTES);
        __bf16* zrow_b = (__bf16*)((char*)d_ws + FEATB_BYTES + WP_BYTES);
        convert_feat_kernel<<<NPTS * CIN / (256 * 8), 256, 0, stream>>>(feat, featb);
        pack_w_kernel<<<NFRAGS / 4 + 1, 256, 0, stream>>>(W, Wp, zrow_b);
        qconv_kernel<<<NPTS / MT, 256, 0, stream>>>(featb, nidx, Wp, bias, out);
    } else {
        qconv_naive<<<NPTS, COUT, 0, stream>>>(feat, nidx, W, bias, out);
    }
}